// Round 1
// baseline (360.580 us; speedup 1.0000x reference)
//
#include <hip/hip_runtime.h>

#define BS_   4096
#define NQ_   21
#define NK_   7
#define E_    512
#define MQ_   (BS_*NQ_)   // 86016 q rows
#define MK_   (BS_*NK_)   // 28672 k rows

typedef __attribute__((ext_vector_type(8))) short bf16x8;
typedef __attribute__((ext_vector_type(4))) float f32x4;
typedef __attribute__((ext_vector_type(4))) unsigned short u16x4;
typedef __attribute__((ext_vector_type(8))) unsigned short u16x8;

__device__ __forceinline__ unsigned short f2bf(float x){
  unsigned int u = __builtin_bit_cast(unsigned int, x);
  return (unsigned short)((u + 0x7FFFu + ((u >> 16) & 1u)) >> 16);   // RNE
}
__device__ __forceinline__ float bf2f(unsigned short h){
  unsigned int u = ((unsigned int)h) << 16;
  return __builtin_bit_cast(float, u);
}
__device__ __forceinline__ void gload_lds16(const void* g, void* l){
  __builtin_amdgcn_global_load_lds(
      (const __attribute__((address_space(1))) unsigned int*)g,
      (__attribute__((address_space(3))) unsigned int*)l, 16, 0, 0);
}
__device__ __forceinline__ float fast_tanh(float x){
  // tanh(x) = 1 - 2/(exp(2x)+1); exp->inf => 1, exp->0 => -1 (correct saturation)
  float e = __expf(2.0f * x);
  return 1.0f - __fdividef(2.0f, e + 1.0f);
}

// ---------------- weight cast f32 -> bf16 ----------------
__global__ __launch_bounds__(256) void cast_weights(
    const float* __restrict__ wq, const float* __restrict__ wk,
    unsigned short* __restrict__ oq, unsigned short* __restrict__ ok)
{
  int i = blockIdx.x * 256 + threadIdx.x;           // 65536 float4s each
  float4 a = ((const float4*)wq)[i];
  float4 b = ((const float4*)wk)[i];
  u16x4 ua, ub;
  ua.x = f2bf(a.x); ua.y = f2bf(a.y); ua.z = f2bf(a.z); ua.w = f2bf(a.w);
  ub.x = f2bf(b.x); ub.y = f2bf(b.y); ub.z = f2bf(b.z); ub.w = f2bf(b.w);
  ((u16x4*)oq)[i] = ua;
  ((u16x4*)ok)[i] = ub;
}

// ---------------- projection GEMM: C[m,h] = sum_e A[m,e]*W[h,e] + bias[h] ----
// A: f32 (M x 512, row-major). W: bf16 (512 x 512, e-contiguous = B^T form).
// 128x128 tile, BK=64, 4 waves (2x2), mfma_f32_16x16x32_bf16, double-buffered.
template<typename ST>
__global__ __launch_bounds__(256, 2)
void gemm_proj(const float* __restrict__ A, const unsigned short* __restrict__ Bw,
               const float* __restrict__ bias, ST* __restrict__ C, int M)
{
  __shared__ unsigned short Asm[2][128 * 64];
  __shared__ unsigned short Bsm[2][128 * 64];

  const int tid  = threadIdx.x;
  const int lane = tid & 63;
  const int w    = tid >> 6;
  const int wr   = w >> 1, wc = w & 1;

  // XCD-bijective swizzle (nwg % 8 == 0 for both M=86016 and M=28672)
  const int nwg = (M >> 7) << 2;
  int bid = (int)blockIdx.x;
  const int q8 = nwg >> 3;
  bid = (bid & 7) * q8 + (bid >> 3);
  const int  mt = bid >> 2, nt = bid & 3;
  const long m0 = (long)mt << 7;
  const int  n0 = nt << 7;

  // A staging map: thread handles float4 (row = a_row + j*16, cols a_c4*4..+3)
  const int a_row = tid >> 4;
  const int a_c4  = tid & 15;
  const float* Abase = A + m0 * E_;

  f32x4 acc[4][4];
  const f32x4 z4 = {0.f, 0.f, 0.f, 0.f};
#pragma unroll
  for (int m = 0; m < 4; ++m)
#pragma unroll
    for (int n = 0; n < 4; ++n) acc[m][n] = z4;

  // ---- prologue: stage K-step 0 into buffer 0
  {
#pragma unroll
    for (int i = 0; i < 4; ++i){
      const int tb  = (w << 12) + (i << 10) + (lane << 4);
      const int row = tb >> 7, cb = tb & 127;
      gload_lds16((const char*)Bw + ((n0 + row) << 10) + cb,
                  (char*)Bsm[0] + (w << 12) + (i << 10));
    }
    float4 av[8];
#pragma unroll
    for (int j = 0; j < 8; ++j)
      av[j] = *(const float4*)(Abase + (long)(a_row + j * 16) * E_ + a_c4 * 4);
#pragma unroll
    for (int j = 0; j < 8; ++j){
      u16x4 u;
      u.x = f2bf(av[j].x); u.y = f2bf(av[j].y); u.z = f2bf(av[j].z); u.w = f2bf(av[j].w);
      *(u16x4*)&Asm[0][(a_row + j * 16) * 64 + a_c4 * 4] = u;
    }
  }
  __syncthreads();

  // ---- main loop: 8 K-steps of 64
#pragma unroll
  for (int t = 0; t < 8; ++t){
    const int buf = t & 1, nbuf = buf ^ 1;
    float4 av[8];
    if (t < 7){
      const int k0 = (t + 1) << 6;
#pragma unroll
      for (int i = 0; i < 4; ++i){
        const int tb  = (w << 12) + (i << 10) + (lane << 4);
        const int row = tb >> 7, cb = tb & 127;
        gload_lds16((const char*)Bw + ((n0 + row) << 10) + (k0 << 1) + cb,
                    (char*)Bsm[nbuf] + (w << 12) + (i << 10));
      }
#pragma unroll
      for (int j = 0; j < 8; ++j)
        av[j] = *(const float4*)(Abase + (long)(a_row + j * 16) * E_ + k0 + a_c4 * 4);
    }
    // compute on buf
#pragma unroll
    for (int kk = 0; kk < 2; ++kk){
      bf16x8 af[4], bfr[4];
#pragma unroll
      for (int m = 0; m < 4; ++m)
        af[m] = *(const bf16x8*)&Asm[buf][(wr * 64 + m * 16 + (lane & 15)) * 64 + kk * 32 + (lane >> 4) * 8];
#pragma unroll
      for (int n = 0; n < 4; ++n)
        bfr[n] = *(const bf16x8*)&Bsm[buf][(wc * 64 + n * 16 + (lane & 15)) * 64 + kk * 32 + (lane >> 4) * 8];
#pragma unroll
      for (int m = 0; m < 4; ++m)
#pragma unroll
        for (int n = 0; n < 4; ++n)
          acc[m][n] = __builtin_amdgcn_mfma_f32_16x16x32_bf16(af[m], bfr[n], acc[m][n], 0, 0, 0);
    }
    if (t < 7){
#pragma unroll
      for (int j = 0; j < 8; ++j){
        u16x4 u;
        u.x = f2bf(av[j].x); u.y = f2bf(av[j].y); u.z = f2bf(av[j].z); u.w = f2bf(av[j].w);
        *(u16x4*)&Asm[nbuf][(a_row + j * 16) * 64 + a_c4 * 4] = u;
      }
    }
    __syncthreads();
  }

  // ---- epilogue: bias + store (C/D layout: col=lane&15, row=(lane>>4)*4+j)
  const int ccol0 = n0 + wc * 64 + (lane & 15);
  float bv[4];
#pragma unroll
  for (int n = 0; n < 4; ++n) bv[n] = bias[ccol0 + n * 16];
#pragma unroll
  for (int m = 0; m < 4; ++m){
    const long rbase = m0 + wr * 64 + m * 16 + (lane >> 4) * 4;
#pragma unroll
    for (int n = 0; n < 4; ++n){
      const long col = ccol0 + n * 16;
#pragma unroll
      for (int j = 0; j < 4; ++j){
        float v = acc[m][n][j] + bv[n];
        if constexpr (sizeof(ST) == 4) C[(rbase + j) * E_ + col] = v;
        else                           C[(rbase + j) * E_ + col] = f2bf(v);
      }
    }
  }
}

// ---------------- fused tanh-score + softmax + weighted sum ----------------
// One block per batch b. ST = storage type of q/k projections (float or bf16).
template<typename ST>
__global__ __launch_bounds__(256, 4)
void attn_fused(const ST* __restrict__ qp, const ST* __restrict__ kp,
                const float* __restrict__ keys, const float* __restrict__ wv,
                const float* __restrict__ wvb, const int* __restrict__ mask,
                float* __restrict__ out0, float* __restrict__ out1)
{
  __shared__ float k_s[NK_ * E_];      // 14 KB: projected keys
  __shared__ float keys_s[NK_ * E_];   // 14 KB: raw keys
  __shared__ float s_s[NQ_ * NK_];
  __shared__ float w_s[NQ_ * NK_];

  const int b    = blockIdx.x;
  const int tid  = threadIdx.x;
  const int lane = tid & 63;
  const int w    = tid >> 6;

  // stage projected k
  if constexpr (sizeof(ST) == 4){
    const float4* src = (const float4*)((const float*)kp + (long)b * NK_ * E_);
    for (int i = tid; i < NK_ * E_ / 4; i += 256) ((float4*)k_s)[i] = src[i];
  } else {
    const u16x8* src = (const u16x8*)((const unsigned short*)kp + (long)b * NK_ * E_);
    for (int i = tid; i < NK_ * E_ / 8; i += 256){
      u16x8 u = src[i];
      float4 lo, hi;
      lo.x = bf2f(u[0]); lo.y = bf2f(u[1]); lo.z = bf2f(u[2]); lo.w = bf2f(u[3]);
      hi.x = bf2f(u[4]); hi.y = bf2f(u[5]); hi.z = bf2f(u[6]); hi.w = bf2f(u[7]);
      ((float4*)k_s)[2 * i]     = lo;
      ((float4*)k_s)[2 * i + 1] = hi;
    }
  }
  {
    const float4* src = (const float4*)(keys + (long)b * NK_ * E_);
    for (int i = tid; i < NK_ * E_ / 4; i += 256) ((float4*)keys_s)[i] = src[i];
  }
  __syncthreads();

  // wv slice per lane (8 contiguous f32)
  float wvr[8];
  *(float4*)&wvr[0] = ((const float4*)wv)[lane * 2];
  *(float4*)&wvr[4] = ((const float4*)wv)[lane * 2 + 1];
  const float vb = wvb[0];

  // scores: wave w owns q rows w, w+4, ...; lanes split H=512 into 8 each
  for (int qi = w; qi < NQ_; qi += 4){
    float qr[8];
    if constexpr (sizeof(ST) == 4){
      const float4* qrow = (const float4*)((const float*)qp + ((long)b * NQ_ + qi) * E_);
      *(float4*)&qr[0] = qrow[lane * 2];
      *(float4*)&qr[4] = qrow[lane * 2 + 1];
    } else {
      u16x8 u = *(const u16x8*)((const unsigned short*)qp + ((long)b * NQ_ + qi) * E_ + lane * 8);
#pragma unroll
      for (int j = 0; j < 8; ++j) qr[j] = bf2f((unsigned short)u[j]);
    }
#pragma unroll
    for (int ki = 0; ki < NK_; ++ki){
      const float* kr = &k_s[ki * E_ + lane * 8];
      float acc = 0.f;
#pragma unroll
      for (int j = 0; j < 8; ++j)
        acc += fast_tanh(qr[j] + kr[j]) * wvr[j];
#pragma unroll
      for (int off = 32; off; off >>= 1) acc += __shfl_xor(acc, off, 64);
      if (lane == 0)
        s_s[qi * NK_ + ki] = acc + vb + (float)mask[b * NK_ + ki] * (-1e9f);
    }
  }
  __syncthreads();

  // softmax over the 7 keys (threads 0..20, one q-row each)
  if (tid < NQ_){
    float sc[NK_], mx = -3.4e38f;
#pragma unroll
    for (int k = 0; k < NK_; ++k){ sc[k] = s_s[tid * NK_ + k]; mx = fmaxf(mx, sc[k]); }
    float sum = 0.f;
#pragma unroll
    for (int k = 0; k < NK_; ++k){ sc[k] = __expf(sc[k] - mx); sum += sc[k]; }
    const float inv = __fdividef(1.0f, sum);
#pragma unroll
    for (int k = 0; k < NK_; ++k) w_s[tid * NK_ + k] = sc[k] * inv;
  }
  __syncthreads();

  // attn_weights out
  if (tid < NQ_ * NK_) out1[(long)b * (NQ_ * NK_) + tid] = w_s[tid];

  // attn_out = weights @ raw keys (float4 epilogue)
  float4* dst = (float4*)(out0 + (long)b * NQ_ * E_);
  for (int idx = tid; idx < NQ_ * (E_ / 4); idx += 256){
    const int qi = idx >> 7, c4 = idx & 127;
    float4 accv = {0.f, 0.f, 0.f, 0.f};
#pragma unroll
    for (int k = 0; k < NK_; ++k){
      const float wgt = w_s[qi * NK_ + k];
      const float4 kv = ((const float4*)keys_s)[k * (E_ / 4) + c4];
      accv.x += wgt * kv.x; accv.y += wgt * kv.y;
      accv.z += wgt * kv.z; accv.w += wgt * kv.w;
    }
    dst[idx] = accv;
  }
}

// ---------------- launcher ----------------
extern "C" void kernel_launch(void* const* d_in, const int* in_sizes, int n_in,
                              void* d_out, int out_size, void* d_ws, size_t ws_size,
                              hipStream_t stream)
{
  const float* queries = (const float*)d_in[0];
  const float* keys    = (const float*)d_in[1];
  const float* wq_w    = (const float*)d_in[2];
  const float* wq_b    = (const float*)d_in[3];
  const float* wk_w    = (const float*)d_in[4];
  const float* wk_b    = (const float*)d_in[5];
  const float* wv_w    = (const float*)d_in[6];
  const float* wv_b    = (const float*)d_in[7];
  const int*   mask    = (const int*)d_in[8];
  (void)in_sizes; (void)n_in;

  float* out0 = (float*)d_out;
  float* out1 = out0 + (long)MQ_ * E_;
  (void)out_size;

  char* ws = (char*)d_ws;
  unsigned short* wqb = (unsigned short*)ws;                       // 512 KB
  unsigned short* wkb = (unsigned short*)(ws + 512 * 512 * 2);     // 512 KB
  char* qkbuf = ws + (1 << 20);

  const size_t qElems = (size_t)MQ_ * E_;
  const size_t kElems = (size_t)MK_ * E_;
  const bool f32ws = ws_size >= (size_t)(1 << 20) + (qElems + kElems) * 4;

  cast_weights<<<dim3(256), dim3(256), 0, stream>>>(wq_w, wk_w, wqb, wkb);

  if (f32ws){
    float* qb = (float*)qkbuf;
    float* kb = qb + qElems;
    gemm_proj<float><<<dim3((MQ_ / 128) * 4), dim3(256), 0, stream>>>(queries, wqb, wq_b, qb, MQ_);
    gemm_proj<float><<<dim3((MK_ / 128) * 4), dim3(256), 0, stream>>>(keys,    wkb, wk_b, kb, MK_);
    attn_fused<float><<<dim3(BS_), dim3(256), 0, stream>>>(qb, kb, keys, wv_w, wv_b, mask, out0, out1);
  } else {
    unsigned short* qb = (unsigned short*)qkbuf;
    unsigned short* kb = qb + qElems;
    gemm_proj<unsigned short><<<dim3((MQ_ / 128) * 4), dim3(256), 0, stream>>>(queries, wqb, wq_b, qb, MQ_);
    gemm_proj<unsigned short><<<dim3((MK_ / 128) * 4), dim3(256), 0, stream>>>(keys,    wkb, wk_b, kb, MK_);
    attn_fused<unsigned short><<<dim3(BS_), dim3(256), 0, stream>>>(qb, kb, keys, wv_w, wv_b, mask, out0, out1);
  }
}

// Round 2
// 302.181 us; speedup vs baseline: 1.1933x; 1.1933x over previous
//
#include <hip/hip_runtime.h>

#define BS_   4096
#define NQ_   21
#define NK_   7
#define E_    512
#define MQ_   (BS_*NQ_)   // 86016 q rows
#define MK_   (BS_*NK_)   // 28672 k rows
#define SCALE_ 2.88539008177792681f   // 2*log2(e): exp2(SCALE*x) = e^{2x}

typedef __attribute__((ext_vector_type(8))) short bf16x8;
typedef __attribute__((ext_vector_type(4))) float f32x4;
typedef __attribute__((ext_vector_type(8))) unsigned short u16x8;

__device__ __forceinline__ unsigned int cvt_pk_bf16(float lo, float hi){
  unsigned int r;
  asm("v_cvt_pk_bf16_f32 %0, %1, %2" : "=v"(r) : "v"(lo), "v"(hi));
  return r;
}
__device__ __forceinline__ float bf2f(unsigned short h){
  return __builtin_bit_cast(float, (unsigned int)h << 16);
}
__device__ __forceinline__ void gload_lds16(const void* g, void* l){
  __builtin_amdgcn_global_load_lds(
      (const __attribute__((address_space(1))) unsigned int*)g,
      (__attribute__((address_space(3))) unsigned int*)l, 16, 0, 0);
}

// ---------------- weight cast f32 -> bf16 ----------------
__global__ __launch_bounds__(256) void cast_weights(
    const float* __restrict__ wq, const float* __restrict__ wk,
    unsigned int* __restrict__ oq, unsigned int* __restrict__ ok)
{
  int i = blockIdx.x * 256 + threadIdx.x;           // 65536 float4s each
  float4 a = ((const float4*)wq)[i];
  float4 b = ((const float4*)wk)[i];
  uint2 ua = { cvt_pk_bf16(a.x, a.y), cvt_pk_bf16(a.z, a.w) };
  uint2 ub = { cvt_pk_bf16(b.x, b.y), cvt_pk_bf16(b.z, b.w) };
  ((uint2*)oq)[i] = ua;
  ((uint2*)ok)[i] = ub;
}

// ---------------- projection GEMM: C[m,h] = (sum_e A[m,e]*W[h,e] + bias[h])*SCALE, bf16 out
__global__ __launch_bounds__(256, 2)
void gemm_proj(const float* __restrict__ A, const unsigned short* __restrict__ Bw,
               const float* __restrict__ bias, unsigned short* __restrict__ C, int M)
{
  __shared__ unsigned short Asm[2][128 * 64];
  __shared__ unsigned short Bsm[2][128 * 64];

  const int tid  = threadIdx.x;
  const int lane = tid & 63;
  const int w    = tid >> 6;
  const int wr   = w >> 1, wc = w & 1;

  // XCD-bijective swizzle (nwg % 8 == 0 for both GEMMs)
  const int nwg = (M >> 7) << 2;
  int bid = (int)blockIdx.x;
  const int q8 = nwg >> 3;
  bid = (bid & 7) * q8 + (bid >> 3);
  const int  mt = bid >> 2, nt = bid & 3;
  const long m0 = (long)mt << 7;
  const int  n0 = nt << 7;

  const int a_row = tid >> 4;
  const int a_c4  = tid & 15;
  const float* Abase = A + m0 * E_;

  f32x4 acc[4][4];
  const f32x4 z4 = {0.f, 0.f, 0.f, 0.f};
#pragma unroll
  for (int m = 0; m < 4; ++m)
#pragma unroll
    for (int n = 0; n < 4; ++n) acc[m][n] = z4;

  // ---- prologue: stage K-step 0 into buffer 0
  {
#pragma unroll
    for (int i = 0; i < 4; ++i){
      const int tb  = (w << 12) + (i << 10) + (lane << 4);
      const int row = tb >> 7, cb = tb & 127;
      gload_lds16((const char*)Bw + ((n0 + row) << 10) + cb,
                  (char*)Bsm[0] + (w << 12) + (i << 10));
    }
    float4 av[8];
#pragma unroll
    for (int j = 0; j < 8; ++j)
      av[j] = *(const float4*)(Abase + (long)(a_row + j * 16) * E_ + a_c4 * 4);
#pragma unroll
    for (int j = 0; j < 8; ++j){
      uint2 u = { cvt_pk_bf16(av[j].x, av[j].y), cvt_pk_bf16(av[j].z, av[j].w) };
      *(uint2*)&Asm[0][(a_row + j * 16) * 64 + a_c4 * 4] = u;
    }
  }
  __syncthreads();

  // ---- main loop: 8 K-steps of 64
#pragma unroll
  for (int t = 0; t < 8; ++t){
    const int buf = t & 1, nbuf = buf ^ 1;
    float4 av[8];
    if (t < 7){
      const int k0 = (t + 1) << 6;
#pragma unroll
      for (int i = 0; i < 4; ++i){
        const int tb  = (w << 12) + (i << 10) + (lane << 4);
        const int row = tb >> 7, cb = tb & 127;
        gload_lds16((const char*)Bw + ((n0 + row) << 10) + (k0 << 1) + cb,
                    (char*)Bsm[nbuf] + (w << 12) + (i << 10));
      }
#pragma unroll
      for (int j = 0; j < 8; ++j)
        av[j] = *(const float4*)(Abase + (long)(a_row + j * 16) * E_ + k0 + a_c4 * 4);
    }
#pragma unroll
    for (int kk = 0; kk < 2; ++kk){
      bf16x8 af[4], bfr[4];
#pragma unroll
      for (int m = 0; m < 4; ++m)
        af[m] = *(const bf16x8*)&Asm[buf][(wr * 64 + m * 16 + (lane & 15)) * 64 + kk * 32 + (lane >> 4) * 8];
#pragma unroll
      for (int n = 0; n < 4; ++n)
        bfr[n] = *(const bf16x8*)&Bsm[buf][(wc * 64 + n * 16 + (lane & 15)) * 64 + kk * 32 + (lane >> 4) * 8];
#pragma unroll
      for (int m = 0; m < 4; ++m)
#pragma unroll
        for (int n = 0; n < 4; ++n)
          acc[m][n] = __builtin_amdgcn_mfma_f32_16x16x32_bf16(af[m], bfr[n], acc[m][n], 0, 0, 0);
    }
    if (t < 7){
#pragma unroll
      for (int j = 0; j < 8; ++j){
        uint2 u = { cvt_pk_bf16(av[j].x, av[j].y), cvt_pk_bf16(av[j].z, av[j].w) };
        *(uint2*)&Asm[nbuf][(a_row + j * 16) * 64 + a_c4 * 4] = u;
      }
    }
    __syncthreads();
  }

  // ---- epilogue: v = (acc + bias)*SCALE, bf16 store
  const int ccol0 = n0 + wc * 64 + (lane & 15);
  float bvs[4];
#pragma unroll
  for (int n = 0; n < 4; ++n) bvs[n] = bias[ccol0 + n * 16] * SCALE_;
#pragma unroll
  for (int m = 0; m < 4; ++m){
    const long rbase = m0 + wr * 64 + m * 16 + (lane >> 4) * 4;
#pragma unroll
    for (int n = 0; n < 4; ++n){
      const long col = ccol0 + n * 16;
      float v0 = fmaf(acc[m][n][0], SCALE_, bvs[n]);
      float v1 = fmaf(acc[m][n][1], SCALE_, bvs[n]);
      float v2 = fmaf(acc[m][n][2], SCALE_, bvs[n]);
      float v3 = fmaf(acc[m][n][3], SCALE_, bvs[n]);
      unsigned int u01 = cvt_pk_bf16(v0, v1);
      unsigned int u23 = cvt_pk_bf16(v2, v3);
      C[(rbase + 0) * E_ + col] = (unsigned short)(u01 & 0xffffu);
      C[(rbase + 1) * E_ + col] = (unsigned short)(u01 >> 16);
      C[(rbase + 2) * E_ + col] = (unsigned short)(u23 & 0xffffu);
      C[(rbase + 3) * E_ + col] = (unsigned short)(u23 >> 16);
    }
  }
}

// ---------------- fused score + softmax + weighted sum ----------------
// One WAVE per batch. q'', k'' are bf16 pre-scaled by 2*log2(e).
// score(q,k) = sum_h wv_h * tanh(q+k) = Wsum - 2*sum_h wv_h / (1 + e^{2(q+k)})
__global__ __launch_bounds__(256, 2)
void attn_fused(const unsigned short* __restrict__ qp,
                const unsigned short* __restrict__ kp,
                const float* __restrict__ keys,
                const float* __restrict__ wv, const float* __restrict__ wvb,
                const int* __restrict__ mask,
                float* __restrict__ out0, float* __restrict__ out1)
{
  const int lane = threadIdx.x & 63;
  const int b    = blockIdx.x * 4 + (threadIdx.x >> 6);

  // per-lane wv slice (h = lane*8 .. +7)
  float wvr[8];
  *(float4*)&wvr[0] = ((const float4*)wv)[lane * 2];
  *(float4*)&wvr[4] = ((const float4*)wv)[lane * 2 + 1];

  // k'' rows -> f32 regs [7][8]
  float kf[NK_][8];
#pragma unroll
  for (int k = 0; k < NK_; ++k){
    u16x8 u = *(const u16x8*)(kp + ((long)b * NK_ + k) * E_ + lane * 8);
#pragma unroll
    for (int j = 0; j < 8; ++j) kf[k][j] = bf2f((unsigned short)u[j]);
  }
  // raw keys -> f32 regs [7][8]
  float kr[NK_][8];
#pragma unroll
  for (int k = 0; k < NK_; ++k){
    const float4* p = (const float4*)(keys + ((long)b * NK_ + k) * E_ + lane * 8);
    *(float4*)&kr[k][0] = p[0];
    *(float4*)&kr[k][4] = p[1];
  }

  // Wsum = sum_h wv_h (butterfly over lanes)
  float wsum = ((wvr[0] + wvr[1]) + (wvr[2] + wvr[3])) + ((wvr[4] + wvr[5]) + (wvr[6] + wvr[7]));
#pragma unroll
  for (int off = 32; off; off >>= 1) wsum += __shfl_xor(wsum, off, 64);

  const float vb = wvb[0];
  float base[NK_];
#pragma unroll
  for (int k = 0; k < NK_; ++k)
    base[k] = (wsum + vb) + (float)mask[b * NK_ + k] * (-1e9f);   // fp32 absorption == ref

  const unsigned short* qrow = qp + (long)b * NQ_ * E_ + lane * 8;
  u16x8 qv = *(const u16x8*)qrow;

  float4* o0 = (float4*)(out0 + (long)b * NQ_ * E_) + lane * 2;
  float*  o1 = out1 + (long)b * (NQ_ * NK_);

  for (int qi = 0; qi < NQ_; ++qi){
    // prefetch next q row (hides HBM latency under this iteration's compute)
    u16x8 qn = qv;
    if (qi < NQ_ - 1) qn = *(const u16x8*)(qrow + (qi + 1) * E_);

    float qf[8];
#pragma unroll
    for (int j = 0; j < 8; ++j) qf[j] = bf2f((unsigned short)qv[j]);
    qv = qn;

    // hot loop: 7 independent accumulator chains
    float acc[NK_];
#pragma unroll
    for (int k = 0; k < NK_; ++k){
      float a = 0.f;
#pragma unroll
      for (int j = 0; j < 8; ++j){
        float x = qf[j] + kf[k][j];                  // 2*log2e*(q+k)
        float e = __builtin_amdgcn_exp2f(x);         // e^{2(q+k)}
        float r = __builtin_amdgcn_rcpf(e + 1.0f);   // sigmoid(-2(q+k))
        a = fmaf(wvr[j], r, a);
      }
      acc[k] = a;
    }
    // 7 independent butterflies (chains pipeline)
#pragma unroll
    for (int k = 0; k < NK_; ++k){
      float a = acc[k];
#pragma unroll
      for (int off = 32; off; off >>= 1) a += __shfl_xor(a, off, 64);
      acc[k] = a;
    }
    // scores + 7-wide softmax (all lanes redundantly, registers only)
    float sc[NK_], mx = -3.4e38f;
#pragma unroll
    for (int k = 0; k < NK_; ++k){ sc[k] = fmaf(-2.f, acc[k], base[k]); mx = fmaxf(mx, sc[k]); }
    float sum = 0.f;
#pragma unroll
    for (int k = 0; k < NK_; ++k){ sc[k] = __expf(sc[k] - mx); sum += sc[k]; }
    const float inv = __builtin_amdgcn_rcpf(sum);
    float wgt[NK_];
#pragma unroll
    for (int k = 0; k < NK_; ++k) wgt[k] = sc[k] * inv;

    // attn_weights: lanes 0..6 write wgt[lane] (branchless select)
    float wsel = wgt[0];
#pragma unroll
    for (int k = 1; k < NK_; ++k) wsel = (lane == k) ? wgt[k] : wsel;
    if (lane < NK_) o1[qi * NK_ + lane] = wsel;

    // attn_out = weights @ raw keys (all in registers)
    float4 lo = {0.f,0.f,0.f,0.f}, hi = {0.f,0.f,0.f,0.f};
#pragma unroll
    for (int k = 0; k < NK_; ++k){
      lo.x = fmaf(wgt[k], kr[k][0], lo.x);
      lo.y = fmaf(wgt[k], kr[k][1], lo.y);
      lo.z = fmaf(wgt[k], kr[k][2], lo.z);
      lo.w = fmaf(wgt[k], kr[k][3], lo.w);
      hi.x = fmaf(wgt[k], kr[k][4], hi.x);
      hi.y = fmaf(wgt[k], kr[k][5], hi.y);
      hi.z = fmaf(wgt[k], kr[k][6], hi.z);
      hi.w = fmaf(wgt[k], kr[k][7], hi.w);
    }
    o0[qi * 128 + 0] = lo;
    o0[qi * 128 + 1] = hi;
  }
}

// ---------------- launcher ----------------
extern "C" void kernel_launch(void* const* d_in, const int* in_sizes, int n_in,
                              void* d_out, int out_size, void* d_ws, size_t ws_size,
                              hipStream_t stream)
{
  const float* queries = (const float*)d_in[0];
  const float* keys    = (const float*)d_in[1];
  const float* wq_w    = (const float*)d_in[2];
  const float* wq_b    = (const float*)d_in[3];
  const float* wk_w    = (const float*)d_in[4];
  const float* wk_b    = (const float*)d_in[5];
  const float* wv_w    = (const float*)d_in[6];
  const float* wv_b    = (const float*)d_in[7];
  const int*   mask    = (const int*)d_in[8];
  (void)in_sizes; (void)n_in; (void)out_size; (void)ws_size;

  float* out0 = (float*)d_out;
  float* out1 = out0 + (long)MQ_ * E_;

  char* ws = (char*)d_ws;
  unsigned short* wqb = (unsigned short*)ws;                       // 512 KB
  unsigned short* wkb = (unsigned short*)(ws + 512 * 512 * 2);     // 512 KB
  unsigned short* qb  = (unsigned short*)(ws + (1 << 20));         // 88.1 MB
  unsigned short* kb  = qb + (size_t)MQ_ * E_;                     // 29.4 MB

  cast_weights<<<dim3(256), dim3(256), 0, stream>>>(wq_w, wk_w, (unsigned int*)wqb, (unsigned int*)wkb);
  gemm_proj<<<dim3((MQ_ / 128) * 4), dim3(256), 0, stream>>>(queries, wqb, wq_b, qb, MQ_);
  gemm_proj<<<dim3((MK_ / 128) * 4), dim3(256), 0, stream>>>(keys,    wkb, wk_b, kb, MK_);
  attn_fused<<<dim3(BS_ / 4), dim3(256), 0, stream>>>(qb, kb, keys, wv_w, wv_b, mask, out0, out1);
}